// Round 15
// baseline (173.564 us; speedup 1.0000x reference)
//
#include <hip/hip_runtime.h>
#include <math.h>

// ---------------------------------------------------------------------------
// Grok5PhiCore: out = proj( softmax(QK^T*scale + phi_bias) V ).
// B=2, L=2048, D=1024, H=16, Dh=64.
//
// v20 (attn: 2-phase double-buffered staging, 1 barrier/tile):
//  - attn adopts v19-proj's proven pattern: {read ALL frags (kf+va) from
//    buf -> issue next tile's DMA into buf^1 -> QK/softmax/PV ->
//    vmcnt(0)+barrier}. Removes v13's per-tile exposed DMA drain (2
//    barriers + serial latency -> 1 barrier, latency hidden under compute).
//    Frag reads precede DMA issue in program order (avoids v11 compiler
//    alias-drain). Grid 512 = 2 blocks/CU => occupancy is grid-limited;
//    early va reads (VGPR ~110-120 < 128) cost nothing. FP order identical.
//  - QKV GEMM = v17 8-phase (validated); proj = v19 2-phase; prep unchanged.
//
// Workspace (48 MB, fp16): xb, wqkvT, wpT, qb, kb, vb(tile-major), ctx.
// ---------------------------------------------------------------------------

typedef _Float16 f16;
typedef _Float16 f16x4 __attribute__((ext_vector_type(4)));
typedef _Float16 f16x8 __attribute__((ext_vector_type(8)));
typedef float f32x4 __attribute__((ext_vector_type(4)));

#define MFMA32(a, b, c) __builtin_amdgcn_mfma_f32_16x16x32_f16(a, b, c, 0, 0, 0)

static constexpr int Bsz = 2, Lseq = 2048, Dm = 1024, H = 16, Dh = 64;
static constexpr int Mtot = Bsz * Lseq;        // 4096
static constexpr int NQKV = 3 * Dm;            // 3072
static constexpr float PHI_F = 1.61803398874989484820f;
static constexpr float LOG2E = 1.44269504088896f;
static constexpr float QS = 0.125f * LOG2E;    // folded into stored q
static constexpr float CSTEP = 0.55417527999932633f;  // fract(64*phi)

// async 16B global -> LDS (lds dest = wave-uniform base + lane*16)
__device__ __forceinline__ void load16_to_lds(const f16* g, f16* l) {
  __builtin_amdgcn_global_load_lds(
      (const __attribute__((address_space(1))) unsigned int*)g,
      (__attribute__((address_space(3))) unsigned int*)l, 16, 0, 0);
}

__device__ __forceinline__ void barrier_fenced() {
  __builtin_amdgcn_sched_barrier(0);
  __builtin_amdgcn_s_barrier();
  __builtin_amdgcn_sched_barrier(0);
}

// ---------------- fused prep: cast + 2 transposes --------------------------
__global__ __launch_bounds__(256) void prep_fused(
    const float* __restrict__ x, f16* __restrict__ xb,
    const float* __restrict__ wqkv, f16* __restrict__ wqkvT,
    const float* __restrict__ wproj, f16* __restrict__ wpT) {
  __shared__ float tile[32][33];
  int blk = blockIdx.x;
  if (blk < 4096) {
    int i = (blk * 256 + threadIdx.x) * 4;
    float4 v = *reinterpret_cast<const float4*>(x + i);
    f16 t[4] = {(f16)v.x, (f16)v.y, (f16)v.z, (f16)v.w};
    *reinterpret_cast<uint2*>(xb + i) = *reinterpret_cast<uint2*>(t);
    return;
  }
  const float* in;
  f16* out;
  int N, bx, by;
  if (blk < 7168) {
    int local = blk - 4096;
    bx = local % 96; by = local / 96; N = NQKV;
    in = wqkv; out = wqkvT;
  } else {
    int local = blk - 7168;
    bx = local & 31; by = local >> 5; N = Dm;
    in = wproj; out = wpT;
  }
  int n0 = bx * 32, k0 = by * 32;
  int tx = threadIdx.x & 31, ty = threadIdx.x >> 5;
#pragma unroll
  for (int r = 0; r < 32; r += 8)
    tile[ty + r][tx] = in[(size_t)(k0 + ty + r) * N + n0 + tx];
  __syncthreads();
#pragma unroll
  for (int r = 0; r < 32; r += 8)
    out[(size_t)(n0 + ty + r) * Dm + k0 + tx] = (f16)tile[tx][ty + r];
}

// ---------------- QKV GEMM: 8-phase 256x192 template (v17) -----------------
// C[4096,3072] = xb[4096,1024] * wqkvT[3072,1024]^T, scatter epilogue.
// grid 256 x 512thr (1 block/CU). XCD decode: 16m x 16n tiles.
__global__ __launch_bounds__(512, 1) void gemm_qkv(
    const f16* __restrict__ A, const f16* __restrict__ Bt,
    f16* __restrict__ qb, f16* __restrict__ kb, f16* __restrict__ vb) {
  __shared__ f16 As[2 * 256 * 64];   // 64KB: [buf][row][64]
  __shared__ f16 Bs[2 * 192 * 64];   // 48KB

  int tid = threadIdx.x;
  int wave = tid >> 6, lane = tid & 63;
  int quad = lane >> 4, l16 = lane & 15;
  int warp_m = wave >> 2, warp_n = wave & 3;
  int wm = warp_m * 128, wn = warp_n * 48;

  int lid = blockIdx.x;
  int xcd = lid & 7, t = lid >> 3;          // t in 0..31
  int mg = xcd & 3, ng = xcd >> 2;
  int m0 = (mg * 4 + (t >> 3)) * 256;       // 16 m-tiles
  int n0 = (ng * 8 + (t & 7)) * 192;        // 16 n-tiles

  const int gu = (lane & 7) ^ (lane >> 3);
  const f16* gAb = A + (size_t)(m0 + wave * 8 + (lane >> 3)) * Dm + gu * 8;
  const f16* gBb = Bt + (size_t)(n0 + wave * 8 + (lane >> 3)) * Dm + gu * 8;

  auto stageA = [&](int buf, int h, int kn) __attribute__((always_inline)) {
#pragma unroll
    for (int i = 0; i < 2; i++)
      load16_to_lds(gAb + (size_t)(h * 128 + i * 64) * Dm + kn,
                    As + buf * 16384 + (h * 128 + i * 64 + wave * 8) * 64);
  };
  auto stageB = [&](int buf, int part, int kn) __attribute__((always_inline)) {
    if (part == 0) {
#pragma unroll
      for (int i = 0; i < 2; i++)
        load16_to_lds(gBb + (size_t)(i * 64) * Dm + kn,
                      Bs + buf * 12288 + (i * 64 + wave * 8) * 64);
    } else {
      load16_to_lds(gBb + (size_t)128 * Dm + kn,
                    Bs + buf * 12288 + (128 + wave * 8) * 64);
    }
  };

  f32x4 acc[8][3] = {};

  auto do_tile = [&](int buf, int t_) __attribute__((always_inline)) {
    const f16* Ab = As + buf * 16384 + (wm + l16) * 64;
    const f16* Bb = Bs + buf * 12288 + (wn + l16) * 64;
    int nbuf = buf ^ 1;
    int kA = ((t_ + 1) & 15) * 64;
    int kB = ((t_ + 2) & 15) * 64;

    f16x8 a[4][2], b0[2][2], b1[2];

    // ---- P1: A-lo frags + B j0,j1 frags; stage A-lo(t+1) ----
#pragma unroll
    for (int m = 0; m < 4; m++)
#pragma unroll
      for (int s = 0; s < 2; s++)
        a[m][s] = *reinterpret_cast<const f16x8*>(
            Ab + m * 16 * 64 + (((s * 4 + quad) ^ (l16 & 7)) * 8));
#pragma unroll
    for (int n = 0; n < 2; n++)
#pragma unroll
      for (int s = 0; s < 2; s++)
        b0[n][s] = *reinterpret_cast<const f16x8*>(
            Bb + n * 16 * 64 + (((s * 4 + quad) ^ (l16 & 7)) * 8));
    stageA(nbuf, 0, kA);
    barrier_fenced();
    asm volatile("s_waitcnt lgkmcnt(0)" ::: "memory");
    __builtin_amdgcn_sched_barrier(0);
    __builtin_amdgcn_s_setprio(1);
#pragma unroll
    for (int m = 0; m < 4; m++)
#pragma unroll
      for (int n = 0; n < 2; n++) {
        acc[m][n] = MFMA32(a[m][0], b0[n][0], acc[m][n]);
        acc[m][n] = MFMA32(a[m][1], b0[n][1], acc[m][n]);
      }
    __builtin_amdgcn_s_setprio(0);
    barrier_fenced();

    // ---- P2: B j2 frags; stage A-hi(t+1) ----
#pragma unroll
    for (int s = 0; s < 2; s++)
      b1[s] = *reinterpret_cast<const f16x8*>(
          Bb + 2 * 16 * 64 + (((s * 4 + quad) ^ (l16 & 7)) * 8));
    stageA(nbuf, 1, kA);
    barrier_fenced();
    asm volatile("s_waitcnt lgkmcnt(0)" ::: "memory");
    __builtin_amdgcn_sched_barrier(0);
    __builtin_amdgcn_s_setprio(1);
#pragma unroll
    for (int m = 0; m < 4; m++) {
      acc[m][2] = MFMA32(a[m][0], b1[0], acc[m][2]);
      acc[m][2] = MFMA32(a[m][1], b1[1], acc[m][2]);
    }
    __builtin_amdgcn_s_setprio(0);
    barrier_fenced();

    // ---- P3: A-hi frags; stage B part0(t+2) ----
#pragma unroll
    for (int m = 0; m < 4; m++)
#pragma unroll
      for (int s = 0; s < 2; s++)
        a[m][s] = *reinterpret_cast<const f16x8*>(
            Ab + (4 + m) * 16 * 64 + (((s * 4 + quad) ^ (l16 & 7)) * 8));
    stageB(buf, 0, kB);
    barrier_fenced();
    asm volatile("s_waitcnt lgkmcnt(0)" ::: "memory");
    __builtin_amdgcn_sched_barrier(0);
    __builtin_amdgcn_s_setprio(1);
#pragma unroll
    for (int m = 0; m < 4; m++)
#pragma unroll
      for (int n = 0; n < 2; n++) {
        acc[4 + m][n] = MFMA32(a[m][0], b0[n][0], acc[4 + m][n]);
        acc[4 + m][n] = MFMA32(a[m][1], b0[n][1], acc[4 + m][n]);
      }
    __builtin_amdgcn_s_setprio(0);
    barrier_fenced();

    // ---- P4: stage B part1(t+2); counted vmcnt(3) ----
    stageB(buf, 1, kB);
    asm volatile("s_waitcnt vmcnt(3)" ::: "memory");  // tile t+1 landed
    barrier_fenced();
    __builtin_amdgcn_s_setprio(1);
#pragma unroll
    for (int m = 0; m < 4; m++) {
      acc[4 + m][2] = MFMA32(a[m][0], b1[0], acc[4 + m][2]);
      acc[4 + m][2] = MFMA32(a[m][1], b1[1], acc[4 + m][2]);
    }
    __builtin_amdgcn_s_setprio(0);
    barrier_fenced();
  };

  stageA(0, 0, 0);
  stageA(0, 1, 0);
  stageB(0, 0, 0);
  stageB(0, 1, 0);
  stageB(1, 0, 64);
  stageB(1, 1, 64);
  asm volatile("s_waitcnt vmcnt(3)" ::: "memory");
  barrier_fenced();

#pragma unroll 1
  for (int tt = 0; tt < 16; tt += 2) {
    do_tile(0, tt);
    do_tile(1, tt + 1);
  }
  asm volatile("s_waitcnt vmcnt(0)" ::: "memory");  // drain dummy stages

  // epilogue (validated v15-v19)
#pragma unroll
  for (int i = 0; i < 8; i++) {
#pragma unroll
    for (int j = 0; j < 3; j++) {
      int n = n0 + wn + j * 16 + l16;
      int ty = n >> 10;  // 0=q 1=k 2=v
      int df = n & 1023;
      int h = df >> 6, dh = df & 63;
      int mb = m0 + wm + i * 16 + quad * 4;  // 4-aligned
      int b = mb >> 11, l = mb & 2047;
      int bhh = b * H + h;
      if (ty == 2) {
        int jj = l & 63;
        int jh = jj >> 5, rem = jj & 31;
        int qd = (rem & 15) >> 2;
        int e0 = (rem >= 16) ? 4 : 0;
        f16x4 tmp;
#pragma unroll
        for (int r = 0; r < 4; r++) tmp[r] = (f16)acc[i][j][r];
        *reinterpret_cast<uint2*>(
            vb + (size_t)bhh * (Dh * Lseq) + (l >> 6) * 4096 + dh * 64 +
            (jh * 4 + qd) * 8 + e0) = *reinterpret_cast<uint2*>(&tmp);
      } else {
        size_t idx = (((size_t)bhh) * Lseq + l) * Dh + dh;
        if (ty == 0) {
#pragma unroll
          for (int r = 0; r < 4; r++)
            qb[idx + (size_t)r * Dh] = (f16)(acc[i][j][r] * QS);
        } else {
#pragma unroll
          for (int r = 0; r < 4; r++)
            kb[idx + (size_t)r * Dh] = (f16)acc[i][j][r];
        }
      }
    }
  }
}

// ---------------- proj GEMM: 128x128 / 4-wave, 2-phase overlap (v19) -------
__global__ __launch_bounds__(256) void gemm_proj(
    const f16* __restrict__ A, const f16* __restrict__ Bt,
    float* __restrict__ out, const float* __restrict__ bias) {
  constexpr int MI = 4, AI = 4;
  __shared__ f16 As[2 * 128 * 64];   // 32KB
  __shared__ f16 Bs[2 * 128 * 64];   // 32KB

  int tid = threadIdx.x;
  int wave = tid >> 6, lane = tid & 63;
  int quad = lane >> 4, l16 = lane & 15;
  int wm = (wave >> 1) * 64, wn = (wave & 1) * 64;

  int lid = blockIdx.x;
  int xcd = lid & 7, t = lid >> 3;          // t in 0..31
  int m0 = (xcd * 4 + (t >> 3)) * 128;      // 32 m-tiles
  int n0 = (t & 7) * 128;                   // 8 n-tiles

  const int gu = (lane & 7) ^ (lane >> 3);
  const f16* gA[AI];
  f16* lA[AI];
#pragma unroll
  for (int i = 0; i < AI; i++) {
    int it = wave * AI + i;
    gA[i] = A + (size_t)(m0 + it * 8 + (lane >> 3)) * Dm + gu * 8;
    lA[i] = As + it * 512;
  }
  const f16* gB[4];
  f16* lB[4];
#pragma unroll
  for (int i = 0; i < 4; i++) {
    int it = wave * 4 + i;
    gB[i] = Bt + (size_t)(n0 + it * 8 + (lane >> 3)) * Dm + gu * 8;
    lB[i] = Bs + it * 512;
  }

  auto stage = [&](int buf, int k0) __attribute__((always_inline)) {
#pragma unroll
    for (int i = 0; i < AI; i++) load16_to_lds(gA[i] + k0, lA[i] + buf * 8192);
#pragma unroll
    for (int i = 0; i < 4; i++) load16_to_lds(gB[i] + k0, lB[i] + buf * 8192);
  };

  f32x4 acc[MI][4] = {};

  stage(0, 0);
  asm volatile("s_waitcnt vmcnt(0)" ::: "memory");
  barrier_fenced();

#pragma unroll 1
  for (int kt = 0; kt < 16; kt++) {
    int buf = kt & 1;
    const f16* Ab = As + buf * 8192;
    const f16* Bb = Bs + buf * 8192;

    f16x8 a[2][MI], b[2][4];
#pragma unroll
    for (int s = 0; s < 2; s++) {
#pragma unroll
      for (int i = 0; i < MI; i++) {
        int row = wm + i * 16 + l16;
        a[s][i] = *reinterpret_cast<const f16x8*>(
            Ab + row * 64 + (((s * 4 + quad) ^ (l16 & 7)) * 8));
      }
#pragma unroll
      for (int j = 0; j < 4; j++) {
        int row = wn + j * 16 + l16;
        b[s][j] = *reinterpret_cast<const f16x8*>(
            Bb + row * 64 + (((s * 4 + quad) ^ (l16 & 7)) * 8));
      }
    }

    int kn = (kt + 1 < 16) ? (kt + 1) * 64 : 0;  // dummy on last
    stage(buf ^ 1, kn);

    __builtin_amdgcn_s_setprio(1);
#pragma unroll
    for (int s = 0; s < 2; s++)
#pragma unroll
      for (int i = 0; i < MI; i++)
#pragma unroll
        for (int j = 0; j < 4; j++)
          acc[i][j] = MFMA32(a[s][i], b[s][j], acc[i][j]);
    __builtin_amdgcn_s_setprio(0);

    asm volatile("s_waitcnt vmcnt(0)" ::: "memory");  // next tile landed
    barrier_fenced();                                 // all reads of buf done
  }

#pragma unroll
  for (int i = 0; i < MI; i++)
#pragma unroll
    for (int j = 0; j < 4; j++) {
      int n = n0 + wn + j * 16 + l16;
#pragma unroll
      for (int r = 0; r < 4; r++) {
        int m = m0 + wm + i * 16 + quad * 4 + r;
        out[(size_t)m * Dm + n] = acc[i][j][r] + bias[n];
      }
    }
}

// ---------------- flash attention v20 (2-phase dbuf, 1 barrier/tile) -------
// grid 512 x 512thr. Decode: bh = (id&7)*4 + ((id>>3)>>4), q0 = ((id>>3)&15)
// *128. Wave w: qq = w&3 (32 q), jhalf = w>>2. Per tile: read kf+va frags
// from buf -> stage(buf^1, t+1) -> QK/softmax/PV -> vmcnt(0)+barrier.
__global__ __launch_bounds__(512, 4) void attn_kernel(
    const f16* __restrict__ qb,   // [BH][L][64], pre-scaled by QS
    const f16* __restrict__ kb,   // [BH][L][64]
    const f16* __restrict__ vb,   // [BH][32 jt][64 d][64 j-perm]
    f16* __restrict__ ctx) {      // [B*L][1024]
  __shared__ __align__(16) unsigned char smem[33280];
  f16* Ks = (f16*)smem;            // [2][64][64] XOR-swizzled chunks
  f16* Vs = (f16*)(smem + 16384);  // [2][64][64] permuted + XOR-swizzled

  int id = blockIdx.x;
  int bh = (id & 7) * 4 + ((id >> 3) >> 4);
  int q0 = ((id >> 3) & 15) * 128;

  int tid = threadIdx.x, wave = tid >> 6, lane = tid & 63;
  int quad = lane >> 4, l16 = lane & 15;
  int jhalf = wave >> 2, qq = wave & 3;

  f16x8 qfrag[2][2];
  float pq[2];
#pragma unroll
  for (int set = 0; set < 2; set++) {
    int q = q0 + qq * 32 + set * 16 + l16;
    const f16* Qrow = qb + ((size_t)bh * Lseq + q) * Dh;
    qfrag[set][0] = *reinterpret_cast<const f16x8*>(Qrow + quad * 8);
    qfrag[set][1] = *reinterpret_cast<const f16x8*>(Qrow + 32 + quad * 8);
    pq[set] = fmodf((float)q * PHI_F, 1.0f);
  }

  float pk[2][4];
#pragma unroll
  for (int jb = 0; jb < 2; jb++)
#pragma unroll
    for (int r = 0; r < 4; r++) {
      int j = jhalf * 32 + jb * 16 + quad * 4 + r;
      pk[jb][r] = fmodf((float)j * PHI_F, 1.0f);
    }

  const f16* Kbh = kb + (size_t)bh * Lseq * Dh;
  const f16* Vbh = vb + (size_t)bh * Dh * Lseq;  // tile-major
  const int gu = (lane & 7) ^ (lane >> 3);
  int g8 = wave * 8 + (lane >> 3);
  const f16* gK = Kbh + (size_t)g8 * Dh + gu * 8;
  const f16* gV = Vbh + (size_t)g8 * 64 + gu * 8;
  f16* lK = Ks + wave * 512;
  f16* lV = Vs + wave * 512;

  auto stage = [&](int buf, int j0) __attribute__((always_inline)) {
    load16_to_lds(gK + (size_t)j0 * Dh, lK + buf * 4096);
    load16_to_lds(gV + (size_t)j0 * 64, lV + buf * 4096);
  };

  const f16 one = (f16)1.0f;
  const f16x8 ones8 = {one, one, one, one, one, one, one, one};

  f32x4 acc_o[2][4] = {};
  f32x4 acc_l[2] = {};

  // LDS frag read bases (buf select via +4096 elems = 8KB)
  const f16* Kfb = Ks + (jhalf * 32 + l16) * 64;
  const f16* Vfb = Vs + l16 * 64 + (((jhalf * 4 + quad) ^ (l16 & 7)) * 8);

  // prologue: tile 0
  stage(0, 0);
  asm volatile("s_waitcnt vmcnt(0)" ::: "memory");
  barrier_fenced();

#pragma unroll 1
  for (int j0 = 0; j0 < Lseq; j0 += 64) {
    int buf = (j0 >> 6) & 1;
    const f16* Kc = Kfb + buf * 4096;
    const f16* Vc = Vfb + buf * 4096;

    // read ALL frags from this buffer FIRST (precede DMA issue)
    f16x8 kf[2][2];
#pragma unroll
    for (int s = 0; s < 2; s++)
#pragma unroll
      for (int jb = 0; jb < 2; jb++)
        kf[s][jb] = *reinterpret_cast<const f16x8*>(
            Kc + jb * 16 * 64 + (((s * 4 + quad) ^ (l16 & 7)) * 8));
    f16x8 va[4];
#pragma unroll
    for (int dblk = 0; dblk < 4; dblk++)
      va[dblk] = *reinterpret_cast<const f16x8*>(Vc + dblk * 16 * 64);

    // prefetch next tile into other buffer (overlaps all compute below)
    int jn = (j0 + 64 < Lseq) ? j0 + 64 : 0;  // dummy on last
    stage(buf ^ 1, jn);

    // S^T = K * Q^T (same FP order as v13/v19)
    f32x4 accs[2][2] = {};
    __builtin_amdgcn_s_setprio(1);
#pragma unroll
    for (int s = 0; s < 2; s++)
#pragma unroll
      for (int jb = 0; jb < 2; jb++) {
        accs[0][jb] = MFMA32(kf[s][jb], qfrag[0][s], accs[0][jb]);
        accs[1][jb] = MFMA32(kf[s][jb], qfrag[1][s], accs[1][jb]);
      }
    __builtin_amdgcn_s_setprio(0);

    f16x8 pf8[2];
#pragma unroll
    for (int set = 0; set < 2; set++) {
#pragma unroll
      for (int jb = 0; jb < 2; jb++) {
        float p[4];
#pragma unroll
        for (int r = 0; r < 4; r++) {
          float d = pq[set] - pk[jb][r];
          float arg = fmaf(-LOG2E, fabsf(d), accs[set][jb][r]);
          p[r] = __builtin_amdgcn_exp2f(arg);
        }
        auto lo = __builtin_amdgcn_cvt_pkrtz(p[0], p[1]);
        auto hi = __builtin_amdgcn_cvt_pkrtz(p[2], p[3]);
        pf8[set][jb * 4 + 0] = lo[0];
        pf8[set][jb * 4 + 1] = lo[1];
        pf8[set][jb * 4 + 2] = hi[0];
        pf8[set][jb * 4 + 3] = hi[1];
      }
      acc_l[set] = MFMA32(ones8, pf8[set], acc_l[set]);
    }
#pragma unroll
    for (int jb = 0; jb < 2; jb++)
#pragma unroll
      for (int r = 0; r < 4; r++)
        pk[jb][r] = __builtin_amdgcn_fractf(pk[jb][r] + CSTEP);

    // O^T += V^T * P^T (same FP order)
    __builtin_amdgcn_s_setprio(1);
#pragma unroll
    for (int dblk = 0; dblk < 4; dblk++) {
      acc_o[0][dblk] = MFMA32(va[dblk], pf8[0], acc_o[0][dblk]);
      acc_o[1][dblk] = MFMA32(va[dblk], pf8[1], acc_o[1][dblk]);
    }
    __builtin_amdgcn_s_setprio(0);

    // next tile landed; all waves done reading buf
    asm volatile("s_waitcnt vmcnt(0)" ::: "memory");
    barrier_fenced();
  }

  // combine jhalf partials: pure adds (static max => no rescale)
  float* Oex = (float*)smem;              // [4 qq][2 set][4 dblk][16][16]
  float* Lex = (float*)(smem + 32768);    // [4 qq][2 set][16]
  if (jhalf == 1) {
#pragma unroll
    for (int set = 0; set < 2; set++) {
#pragma unroll
      for (int dblk = 0; dblk < 4; dblk++)
#pragma unroll
        for (int r = 0; r < 4; r++)
          Oex[(((qq * 2 + set) * 4 + dblk) * 16 + quad * 4 + r) * 16 + l16] =
              acc_o[set][dblk][r];
      if (quad == 0) Lex[(qq * 2 + set) * 16 + l16] = acc_l[set][0];
    }
  }
  __syncthreads();
  if (jhalf == 0) {
    int b = bh >> 4, h = bh & 15;
#pragma unroll
    for (int set = 0; set < 2; set++) {
      float ltot = acc_l[set][0] + Lex[(qq * 2 + set) * 16 + l16];
      float inv = 1.0f / ltot;
      int q = q0 + qq * 32 + set * 16 + l16;
      f16* crow = ctx + (size_t)(b * Lseq + q) * Dm + h * 64;
#pragma unroll
      for (int dblk = 0; dblk < 4; dblk++) {
        f16x4 o;
#pragma unroll
        for (int r = 0; r < 4; r++) {
          float full = acc_o[set][dblk][r] +
              Oex[(((qq * 2 + set) * 4 + dblk) * 16 + quad * 4 + r) * 16 + l16];
          o[r] = (f16)(full * inv);
        }
        *reinterpret_cast<uint2*>(crow + dblk * 16 + quad * 4) =
            *reinterpret_cast<uint2*>(&o);
      }
    }
  }
}

// ---------------------------------------------------------------------------
extern "C" void kernel_launch(void* const* d_in, const int* in_sizes, int n_in,
                              void* d_out, int out_size, void* d_ws, size_t ws_size,
                              hipStream_t stream) {
  const float* x      = (const float*)d_in[0];  // [2,2048,1024]
  const float* w_qkv  = (const float*)d_in[1];  // [1024,3072]
  const float* w_proj = (const float*)d_in[2];  // [1024,1024]
  const float* b_proj = (const float*)d_in[3];  // [1024]
  float* out = (float*)d_out;                   // [2,2048,1024]

  f16* xb    = (f16*)d_ws;                       // 4096*1024
  f16* wqkvT = xb + (size_t)Mtot * Dm;           // 3072*1024
  f16* wpT   = wqkvT + (size_t)NQKV * Dm;        // 1024*1024
  f16* qb    = wpT + (size_t)Dm * Dm;            // 32*2048*64
  f16* kb    = qb + (size_t)Bsz * H * Lseq * Dh;
  f16* vb    = kb + (size_t)Bsz * H * Lseq * Dh; // tile-major j-permuted
  f16* ctx   = vb + (size_t)Bsz * H * Lseq * Dh; // attn output

  prep_fused<<<8192, 256, 0, stream>>>(x, xb, w_qkv, wqkvT, w_proj, wpT);

  gemm_qkv<<<256, 512, 0, stream>>>(xb, wqkvT, qb, kb, vb);

  attn_kernel<<<512, 512, 0, stream>>>(qb, kb, vb, ctx);

  gemm_proj<<<256, 256, 0, stream>>>(ctx, wpT, out, b_proj);
}

// Round 16
// 171.592 us; speedup vs baseline: 1.0115x; 1.0115x over previous
//
#include <hip/hip_runtime.h>
#include <math.h>

// ---------------------------------------------------------------------------
// Grok5PhiCore: out = proj( softmax(QK^T*scale + phi_bias) V ).
// B=2, L=2048, D=1024, H=16, Dh=64.
//
// v21 (proj occupancy + tail cleanup):
//  - gemm_proj: BM=128, BN=64 -> grid 512 = 2 blocks/CU = 8 waves/CU (was
//    256 blocks = 1/CU = 4 waves/CU, i.e. 1 wave/SIMD -- the worst
//    latency-hiding config). Same staging idiom, XOR swizzle, 2-phase
//    overlap, same per-accumulator K order -> bitwise-same output.
//    LDS 48KB/block.
//  - attn/proj: wrap dummy-stages predicated away (no tail L2 reads).
//  - attn = v20 2-phase dbuf (best measured, 50.5us); QKV = v17 8-phase;
//    prep unchanged.
//
// Workspace (48 MB, fp16): xb, wqkvT, wpT, qb, kb, vb(tile-major), ctx.
// ---------------------------------------------------------------------------

typedef _Float16 f16;
typedef _Float16 f16x4 __attribute__((ext_vector_type(4)));
typedef _Float16 f16x8 __attribute__((ext_vector_type(8)));
typedef float f32x4 __attribute__((ext_vector_type(4)));

#define MFMA32(a, b, c) __builtin_amdgcn_mfma_f32_16x16x32_f16(a, b, c, 0, 0, 0)

static constexpr int Bsz = 2, Lseq = 2048, Dm = 1024, H = 16, Dh = 64;
static constexpr int Mtot = Bsz * Lseq;        // 4096
static constexpr int NQKV = 3 * Dm;            // 3072
static constexpr float PHI_F = 1.61803398874989484820f;
static constexpr float LOG2E = 1.44269504088896f;
static constexpr float QS = 0.125f * LOG2E;    // folded into stored q
static constexpr float CSTEP = 0.55417527999932633f;  // fract(64*phi)

// async 16B global -> LDS (lds dest = wave-uniform base + lane*16)
__device__ __forceinline__ void load16_to_lds(const f16* g, f16* l) {
  __builtin_amdgcn_global_load_lds(
      (const __attribute__((address_space(1))) unsigned int*)g,
      (__attribute__((address_space(3))) unsigned int*)l, 16, 0, 0);
}

__device__ __forceinline__ void barrier_fenced() {
  __builtin_amdgcn_sched_barrier(0);
  __builtin_amdgcn_s_barrier();
  __builtin_amdgcn_sched_barrier(0);
}

// ---------------- fused prep: cast + 2 transposes --------------------------
__global__ __launch_bounds__(256) void prep_fused(
    const float* __restrict__ x, f16* __restrict__ xb,
    const float* __restrict__ wqkv, f16* __restrict__ wqkvT,
    const float* __restrict__ wproj, f16* __restrict__ wpT) {
  __shared__ float tile[32][33];
  int blk = blockIdx.x;
  if (blk < 4096) {
    int i = (blk * 256 + threadIdx.x) * 4;
    float4 v = *reinterpret_cast<const float4*>(x + i);
    f16 t[4] = {(f16)v.x, (f16)v.y, (f16)v.z, (f16)v.w};
    *reinterpret_cast<uint2*>(xb + i) = *reinterpret_cast<uint2*>(t);
    return;
  }
  const float* in;
  f16* out;
  int N, bx, by;
  if (blk < 7168) {
    int local = blk - 4096;
    bx = local % 96; by = local / 96; N = NQKV;
    in = wqkv; out = wqkvT;
  } else {
    int local = blk - 7168;
    bx = local & 31; by = local >> 5; N = Dm;
    in = wproj; out = wpT;
  }
  int n0 = bx * 32, k0 = by * 32;
  int tx = threadIdx.x & 31, ty = threadIdx.x >> 5;
#pragma unroll
  for (int r = 0; r < 32; r += 8)
    tile[ty + r][tx] = in[(size_t)(k0 + ty + r) * N + n0 + tx];
  __syncthreads();
#pragma unroll
  for (int r = 0; r < 32; r += 8)
    out[(size_t)(n0 + ty + r) * Dm + k0 + tx] = (f16)tile[tx][ty + r];
}

// ---------------- QKV GEMM: 8-phase 256x192 template (v17) -----------------
__global__ __launch_bounds__(512, 1) void gemm_qkv(
    const f16* __restrict__ A, const f16* __restrict__ Bt,
    f16* __restrict__ qb, f16* __restrict__ kb, f16* __restrict__ vb) {
  __shared__ f16 As[2 * 256 * 64];   // 64KB: [buf][row][64]
  __shared__ f16 Bs[2 * 192 * 64];   // 48KB

  int tid = threadIdx.x;
  int wave = tid >> 6, lane = tid & 63;
  int quad = lane >> 4, l16 = lane & 15;
  int warp_m = wave >> 2, warp_n = wave & 3;
  int wm = warp_m * 128, wn = warp_n * 48;

  int lid = blockIdx.x;
  int xcd = lid & 7, t = lid >> 3;          // t in 0..31
  int mg = xcd & 3, ng = xcd >> 2;
  int m0 = (mg * 4 + (t >> 3)) * 256;       // 16 m-tiles
  int n0 = (ng * 8 + (t & 7)) * 192;        // 16 n-tiles

  const int gu = (lane & 7) ^ (lane >> 3);
  const f16* gAb = A + (size_t)(m0 + wave * 8 + (lane >> 3)) * Dm + gu * 8;
  const f16* gBb = Bt + (size_t)(n0 + wave * 8 + (lane >> 3)) * Dm + gu * 8;

  auto stageA = [&](int buf, int h, int kn) __attribute__((always_inline)) {
#pragma unroll
    for (int i = 0; i < 2; i++)
      load16_to_lds(gAb + (size_t)(h * 128 + i * 64) * Dm + kn,
                    As + buf * 16384 + (h * 128 + i * 64 + wave * 8) * 64);
  };
  auto stageB = [&](int buf, int part, int kn) __attribute__((always_inline)) {
    if (part == 0) {
#pragma unroll
      for (int i = 0; i < 2; i++)
        load16_to_lds(gBb + (size_t)(i * 64) * Dm + kn,
                      Bs + buf * 12288 + (i * 64 + wave * 8) * 64);
    } else {
      load16_to_lds(gBb + (size_t)128 * Dm + kn,
                    Bs + buf * 12288 + (128 + wave * 8) * 64);
    }
  };

  f32x4 acc[8][3] = {};

  auto do_tile = [&](int buf, int t_) __attribute__((always_inline)) {
    const f16* Ab = As + buf * 16384 + (wm + l16) * 64;
    const f16* Bb = Bs + buf * 12288 + (wn + l16) * 64;
    int nbuf = buf ^ 1;
    int kA = ((t_ + 1) & 15) * 64;
    int kB = ((t_ + 2) & 15) * 64;

    f16x8 a[4][2], b0[2][2], b1[2];

    // ---- P1: A-lo frags + B j0,j1 frags; stage A-lo(t+1) ----
#pragma unroll
    for (int m = 0; m < 4; m++)
#pragma unroll
      for (int s = 0; s < 2; s++)
        a[m][s] = *reinterpret_cast<const f16x8*>(
            Ab + m * 16 * 64 + (((s * 4 + quad) ^ (l16 & 7)) * 8));
#pragma unroll
    for (int n = 0; n < 2; n++)
#pragma unroll
      for (int s = 0; s < 2; s++)
        b0[n][s] = *reinterpret_cast<const f16x8*>(
            Bb + n * 16 * 64 + (((s * 4 + quad) ^ (l16 & 7)) * 8));
    stageA(nbuf, 0, kA);
    barrier_fenced();
    asm volatile("s_waitcnt lgkmcnt(0)" ::: "memory");
    __builtin_amdgcn_sched_barrier(0);
    __builtin_amdgcn_s_setprio(1);
#pragma unroll
    for (int m = 0; m < 4; m++)
#pragma unroll
      for (int n = 0; n < 2; n++) {
        acc[m][n] = MFMA32(a[m][0], b0[n][0], acc[m][n]);
        acc[m][n] = MFMA32(a[m][1], b0[n][1], acc[m][n]);
      }
    __builtin_amdgcn_s_setprio(0);
    barrier_fenced();

    // ---- P2: B j2 frags; stage A-hi(t+1) ----
#pragma unroll
    for (int s = 0; s < 2; s++)
      b1[s] = *reinterpret_cast<const f16x8*>(
          Bb + 2 * 16 * 64 + (((s * 4 + quad) ^ (l16 & 7)) * 8));
    stageA(nbuf, 1, kA);
    barrier_fenced();
    asm volatile("s_waitcnt lgkmcnt(0)" ::: "memory");
    __builtin_amdgcn_sched_barrier(0);
    __builtin_amdgcn_s_setprio(1);
#pragma unroll
    for (int m = 0; m < 4; m++) {
      acc[m][2] = MFMA32(a[m][0], b1[0], acc[m][2]);
      acc[m][2] = MFMA32(a[m][1], b1[1], acc[m][2]);
    }
    __builtin_amdgcn_s_setprio(0);
    barrier_fenced();

    // ---- P3: A-hi frags; stage B part0(t+2) ----
#pragma unroll
    for (int m = 0; m < 4; m++)
#pragma unroll
      for (int s = 0; s < 2; s++)
        a[m][s] = *reinterpret_cast<const f16x8*>(
            Ab + (4 + m) * 16 * 64 + (((s * 4 + quad) ^ (l16 & 7)) * 8));
    stageB(buf, 0, kB);
    barrier_fenced();
    asm volatile("s_waitcnt lgkmcnt(0)" ::: "memory");
    __builtin_amdgcn_sched_barrier(0);
    __builtin_amdgcn_s_setprio(1);
#pragma unroll
    for (int m = 0; m < 4; m++)
#pragma unroll
      for (int n = 0; n < 2; n++) {
        acc[4 + m][n] = MFMA32(a[m][0], b0[n][0], acc[4 + m][n]);
        acc[4 + m][n] = MFMA32(a[m][1], b0[n][1], acc[4 + m][n]);
      }
    __builtin_amdgcn_s_setprio(0);
    barrier_fenced();

    // ---- P4: stage B part1(t+2); counted vmcnt(3) ----
    stageB(buf, 1, kB);
    asm volatile("s_waitcnt vmcnt(3)" ::: "memory");  // tile t+1 landed
    barrier_fenced();
    __builtin_amdgcn_s_setprio(1);
#pragma unroll
    for (int m = 0; m < 4; m++) {
      acc[4 + m][2] = MFMA32(a[m][0], b1[0], acc[4 + m][2]);
      acc[4 + m][2] = MFMA32(a[m][1], b1[1], acc[4 + m][2]);
    }
    __builtin_amdgcn_s_setprio(0);
    barrier_fenced();
  };

  stageA(0, 0, 0);
  stageA(0, 1, 0);
  stageB(0, 0, 0);
  stageB(0, 1, 0);
  stageB(1, 0, 64);
  stageB(1, 1, 64);
  asm volatile("s_waitcnt vmcnt(3)" ::: "memory");
  barrier_fenced();

#pragma unroll 1
  for (int tt = 0; tt < 16; tt += 2) {
    do_tile(0, tt);
    do_tile(1, tt + 1);
  }
  asm volatile("s_waitcnt vmcnt(0)" ::: "memory");  // drain dummy stages

  // epilogue (validated v15-v20)
#pragma unroll
  for (int i = 0; i < 8; i++) {
#pragma unroll
    for (int j = 0; j < 3; j++) {
      int n = n0 + wn + j * 16 + l16;
      int ty = n >> 10;  // 0=q 1=k 2=v
      int df = n & 1023;
      int h = df >> 6, dh = df & 63;
      int mb = m0 + wm + i * 16 + quad * 4;  // 4-aligned
      int b = mb >> 11, l = mb & 2047;
      int bhh = b * H + h;
      if (ty == 2) {
        int jj = l & 63;
        int jh = jj >> 5, rem = jj & 31;
        int qd = (rem & 15) >> 2;
        int e0 = (rem >= 16) ? 4 : 0;
        f16x4 tmp;
#pragma unroll
        for (int r = 0; r < 4; r++) tmp[r] = (f16)acc[i][j][r];
        *reinterpret_cast<uint2*>(
            vb + (size_t)bhh * (Dh * Lseq) + (l >> 6) * 4096 + dh * 64 +
            (jh * 4 + qd) * 8 + e0) = *reinterpret_cast<uint2*>(&tmp);
      } else {
        size_t idx = (((size_t)bhh) * Lseq + l) * Dh + dh;
        if (ty == 0) {
#pragma unroll
          for (int r = 0; r < 4; r++)
            qb[idx + (size_t)r * Dh] = (f16)(acc[i][j][r] * QS);
        } else {
#pragma unroll
          for (int r = 0; r < 4; r++)
            kb[idx + (size_t)r * Dh] = (f16)acc[i][j][r];
        }
      }
    }
  }
}

// ---------------- proj GEMM: 128x64 / 4-wave, 2-phase, grid 512 ------------
// out[4096,1024] = ctx[4096,1024] * wpT[1024,1024]^T + bias, fp32 out.
// grid 512 x 256thr = 2 blocks/CU = 8 waves/CU (was 4). LDS 48KB.
// XCD decode: 32m x 16n tiles; per XCD 4m x 16n.
__global__ __launch_bounds__(256) void gemm_proj(
    const f16* __restrict__ A, const f16* __restrict__ Bt,
    float* __restrict__ out, const float* __restrict__ bias) {
  constexpr int MI = 4;  // m-frags per wave (64 rows)
  __shared__ f16 As[2 * 128 * 64];   // 32KB
  __shared__ f16 Bs[2 * 64 * 64];    // 16KB

  int tid = threadIdx.x;
  int wave = tid >> 6, lane = tid & 63;
  int quad = lane >> 4, l16 = lane & 15;
  int wm = (wave >> 1) * 64, wn = (wave & 1) * 32;

  int lid = blockIdx.x;
  int xcd = lid & 7, t = lid >> 3;          // t in 0..63
  int m0 = (xcd * 4 + (t >> 4)) * 128;      // 32 m-tiles
  int n0 = (t & 15) * 64;                   // 16 n-tiles

  const int gu = (lane & 7) ^ (lane >> 3);
  const f16* gA[4];
  f16* lA[4];
#pragma unroll
  for (int i = 0; i < 4; i++) {
    int it = wave * 4 + i;                  // 16 slices of 8 rows = 128
    gA[i] = A + (size_t)(m0 + it * 8 + (lane >> 3)) * Dm + gu * 8;
    lA[i] = As + it * 512;
  }
  const f16* gB[2];
  f16* lB[2];
#pragma unroll
  for (int i = 0; i < 2; i++) {
    int it = wave * 2 + i;                  // 8 slices of 8 rows = 64
    gB[i] = Bt + (size_t)(n0 + it * 8 + (lane >> 3)) * Dm + gu * 8;
    lB[i] = Bs + it * 512;
  }

  auto stage = [&](int buf, int k0) __attribute__((always_inline)) {
#pragma unroll
    for (int i = 0; i < 4; i++) load16_to_lds(gA[i] + k0, lA[i] + buf * 8192);
#pragma unroll
    for (int i = 0; i < 2; i++) load16_to_lds(gB[i] + k0, lB[i] + buf * 4096);
  };

  f32x4 acc[MI][2] = {};

  stage(0, 0);
  asm volatile("s_waitcnt vmcnt(0)" ::: "memory");
  barrier_fenced();

#pragma unroll 1
  for (int kt = 0; kt < 16; kt++) {
    int buf = kt & 1;
    const f16* Ab = As + buf * 8192;
    const f16* Bb = Bs + buf * 4096;

    // read all frags from buf FIRST (precede DMA issue in program order)
    f16x8 a[2][MI], b[2][2];
#pragma unroll
    for (int s = 0; s < 2; s++) {
#pragma unroll
      for (int i = 0; i < MI; i++) {
        int row = wm + i * 16 + l16;
        a[s][i] = *reinterpret_cast<const f16x8*>(
            Ab + row * 64 + (((s * 4 + quad) ^ (l16 & 7)) * 8));
      }
#pragma unroll
      for (int j = 0; j < 2; j++) {
        int row = wn + j * 16 + l16;
        b[s][j] = *reinterpret_cast<const f16x8*>(
            Bb + row * 64 + (((s * 4 + quad) ^ (l16 & 7)) * 8));
      }
    }

    // prefetch next tile (predicated: no dummy on last)
    if (kt + 1 < 16) stage(buf ^ 1, (kt + 1) * 64);

    __builtin_amdgcn_s_setprio(1);
#pragma unroll
    for (int s = 0; s < 2; s++)
#pragma unroll
      for (int i = 0; i < MI; i++)
#pragma unroll
        for (int j = 0; j < 2; j++)
          acc[i][j] = MFMA32(a[s][i], b[s][j], acc[i][j]);
    __builtin_amdgcn_s_setprio(0);

    asm volatile("s_waitcnt vmcnt(0)" ::: "memory");  // next tile landed
    barrier_fenced();                                 // all reads of buf done
  }

#pragma unroll
  for (int i = 0; i < MI; i++)
#pragma unroll
    for (int j = 0; j < 2; j++) {
      int n = n0 + wn + j * 16 + l16;
#pragma unroll
      for (int r = 0; r < 4; r++) {
        int m = m0 + wm + i * 16 + quad * 4 + r;
        out[(size_t)m * Dm + n] = acc[i][j][r] + bias[n];
      }
    }
}

// ---------------- flash attention v20 (2-phase dbuf, 1 barrier/tile) -------
__global__ __launch_bounds__(512, 4) void attn_kernel(
    const f16* __restrict__ qb,   // [BH][L][64], pre-scaled by QS
    const f16* __restrict__ kb,   // [BH][L][64]
    const f16* __restrict__ vb,   // [BH][32 jt][64 d][64 j-perm]
    f16* __restrict__ ctx) {      // [B*L][1024]
  __shared__ __align__(16) unsigned char smem[33280];
  f16* Ks = (f16*)smem;            // [2][64][64] XOR-swizzled chunks
  f16* Vs = (f16*)(smem + 16384);  // [2][64][64] permuted + XOR-swizzled

  int id = blockIdx.x;
  int bh = (id & 7) * 4 + ((id >> 3) >> 4);
  int q0 = ((id >> 3) & 15) * 128;

  int tid = threadIdx.x, wave = tid >> 6, lane = tid & 63;
  int quad = lane >> 4, l16 = lane & 15;
  int jhalf = wave >> 2, qq = wave & 3;

  f16x8 qfrag[2][2];
  float pq[2];
#pragma unroll
  for (int set = 0; set < 2; set++) {
    int q = q0 + qq * 32 + set * 16 + l16;
    const f16* Qrow = qb + ((size_t)bh * Lseq + q) * Dh;
    qfrag[set][0] = *reinterpret_cast<const f16x8*>(Qrow + quad * 8);
    qfrag[set][1] = *reinterpret_cast<const f16x8*>(Qrow + 32 + quad * 8);
    pq[set] = fmodf((float)q * PHI_F, 1.0f);
  }

  float pk[2][4];
#pragma unroll
  for (int jb = 0; jb < 2; jb++)
#pragma unroll
    for (int r = 0; r < 4; r++) {
      int j = jhalf * 32 + jb * 16 + quad * 4 + r;
      pk[jb][r] = fmodf((float)j * PHI_F, 1.0f);
    }

  const f16* Kbh = kb + (size_t)bh * Lseq * Dh;
  const f16* Vbh = vb + (size_t)bh * Dh * Lseq;  // tile-major
  const int gu = (lane & 7) ^ (lane >> 3);
  int g8 = wave * 8 + (lane >> 3);
  const f16* gK = Kbh + (size_t)g8 * Dh + gu * 8;
  const f16* gV = Vbh + (size_t)g8 * 64 + gu * 8;
  f16* lK = Ks + wave * 512;
  f16* lV = Vs + wave * 512;

  auto stage = [&](int buf, int j0) __attribute__((always_inline)) {
    load16_to_lds(gK + (size_t)j0 * Dh, lK + buf * 4096);
    load16_to_lds(gV + (size_t)j0 * 64, lV + buf * 4096);
  };

  const f16 one = (f16)1.0f;
  const f16x8 ones8 = {one, one, one, one, one, one, one, one};

  f32x4 acc_o[2][4] = {};
  f32x4 acc_l[2] = {};

  // LDS frag read bases (buf select via +4096 elems = 8KB)
  const f16* Kfb = Ks + (jhalf * 32 + l16) * 64;
  const f16* Vfb = Vs + l16 * 64 + (((jhalf * 4 + quad) ^ (l16 & 7)) * 8);

  // prologue: tile 0
  stage(0, 0);
  asm volatile("s_waitcnt vmcnt(0)" ::: "memory");
  barrier_fenced();

#pragma unroll 1
  for (int j0 = 0; j0 < Lseq; j0 += 64) {
    int buf = (j0 >> 6) & 1;
    const f16* Kc = Kfb + buf * 4096;
    const f16* Vc = Vfb + buf * 4096;

    // read ALL frags from this buffer FIRST (precede DMA issue)
    f16x8 kf[2][2];
#pragma unroll
    for (int s = 0; s < 2; s++)
#pragma unroll
      for (int jb = 0; jb < 2; jb++)
        kf[s][jb] = *reinterpret_cast<const f16x8*>(
            Kc + jb * 16 * 64 + (((s * 4 + quad) ^ (l16 & 7)) * 8));
    f16x8 va[4];
#pragma unroll
    for (int dblk = 0; dblk < 4; dblk++)
      va[dblk] = *reinterpret_cast<const f16x8*>(Vc + dblk * 16 * 64);

    // prefetch next tile into other buffer (predicated: no dummy on last)
    if (j0 + 64 < Lseq) stage(buf ^ 1, j0 + 64);

    // S^T = K * Q^T (same FP order as v13/v19/v20)
    f32x4 accs[2][2] = {};
    __builtin_amdgcn_s_setprio(1);
#pragma unroll
    for (int s = 0; s < 2; s++)
#pragma unroll
      for (int jb = 0; jb < 2; jb++) {
        accs[0][jb] = MFMA32(kf[s][jb], qfrag[0][s], accs[0][jb]);
        accs[1][jb] = MFMA32(kf[s][jb], qfrag[1][s], accs[1][jb]);
      }
    __builtin_amdgcn_s_setprio(0);

    f16x8 pf8[2];
#pragma unroll
    for (int set = 0; set < 2; set++) {
#pragma unroll
      for (int jb = 0; jb < 2; jb++) {
        float p[4];
#pragma unroll
        for (int r = 0; r < 4; r++) {
          float d = pq[set] - pk[jb][r];
          float arg = fmaf(-LOG2E, fabsf(d), accs[set][jb][r]);
          p[r] = __builtin_amdgcn_exp2f(arg);
        }
        auto lo = __builtin_amdgcn_cvt_pkrtz(p[0], p[1]);
        auto hi = __builtin_amdgcn_cvt_pkrtz(p[2], p[3]);
        pf8[set][jb * 4 + 0] = lo[0];
        pf8[set][jb * 4 + 1] = lo[1];
        pf8[set][jb * 4 + 2] = hi[0];
        pf8[set][jb * 4 + 3] = hi[1];
      }
      acc_l[set] = MFMA32(ones8, pf8[set], acc_l[set]);
    }
#pragma unroll
    for (int jb = 0; jb < 2; jb++)
#pragma unroll
      for (int r = 0; r < 4; r++)
        pk[jb][r] = __builtin_amdgcn_fractf(pk[jb][r] + CSTEP);

    // O^T += V^T * P^T (same FP order)
    __builtin_amdgcn_s_setprio(1);
#pragma unroll
    for (int dblk = 0; dblk < 4; dblk++) {
      acc_o[0][dblk] = MFMA32(va[dblk], pf8[0], acc_o[0][dblk]);
      acc_o[1][dblk] = MFMA32(va[dblk], pf8[1], acc_o[1][dblk]);
    }
    __builtin_amdgcn_s_setprio(0);

    // next tile landed; all waves done reading buf
    asm volatile("s_waitcnt vmcnt(0)" ::: "memory");
    barrier_fenced();
  }

  // combine jhalf partials: pure adds (static max => no rescale)
  float* Oex = (float*)smem;              // [4 qq][2 set][4 dblk][16][16]
  float* Lex = (float*)(smem + 32768);    // [4 qq][2 set][16]
  if (jhalf == 1) {
#pragma unroll
    for (int set = 0; set < 2; set++) {
#pragma unroll
      for (int dblk = 0; dblk < 4; dblk++)
#pragma unroll
        for (int r = 0; r < 4; r++)
          Oex[(((qq * 2 + set) * 4 + dblk) * 16 + quad * 4 + r) * 16 + l16] =
              acc_o[set][dblk][r];
      if (quad == 0) Lex[(qq * 2 + set) * 16 + l16] = acc_l[set][0];
    }
  }
  __syncthreads();
  if (jhalf == 0) {
    int b = bh >> 4, h = bh & 15;
#pragma unroll
    for (int set = 0; set < 2; set++) {
      float ltot = acc_l[set][0] + Lex[(qq * 2 + set) * 16 + l16];
      float inv = 1.0f / ltot;
      int q = q0 + qq * 32 + set * 16 + l16;
      f16* crow = ctx + (size_t)(b * Lseq + q) * Dm + h * 64;
#pragma unroll
      for (int dblk = 0; dblk < 4; dblk++) {
        f16x4 o;
#pragma unroll
        for (int r = 0; r < 4; r++) {
          float full = acc_o[set][dblk][r] +
              Oex[(((qq * 2 + set) * 4 + dblk) * 16 + quad * 4 + r) * 16 + l16];
          o[r] = (f16)(full * inv);
        }
        *reinterpret_cast<uint2*>(crow + dblk * 16 + quad * 4) =
            *reinterpret_cast<uint2*>(&o);
      }
    }
  }
}

// ---------------------------------------------------------------------------
extern "C" void kernel_launch(void* const* d_in, const int* in_sizes, int n_in,
                              void* d_out, int out_size, void* d_ws, size_t ws_size,
                              hipStream_t stream) {
  const float* x      = (const float*)d_in[0];  // [2,2048,1024]
  const float* w_qkv  = (const float*)d_in[1];  // [1024,3072]
  const float* w_proj = (const float*)d_in[2];  // [1024,1024]
  const float* b_proj = (const float*)d_in[3];  // [1024]
  float* out = (float*)d_out;                   // [2,2048,1024]

  f16* xb    = (f16*)d_ws;                       // 4096*1024
  f16* wqkvT = xb + (size_t)Mtot * Dm;           // 3072*1024
  f16* wpT   = wqkvT + (size_t)NQKV * Dm;        // 1024*1024
  f16* qb    = wpT + (size_t)Dm * Dm;            // 32*2048*64
  f16* kb    = qb + (size_t)Bsz * H * Lseq * Dh;
  f16* vb    = kb + (size_t)Bsz * H * Lseq * Dh; // tile-major j-permuted
  f16* ctx   = vb + (size_t)Bsz * H * Lseq * Dh; // attn output

  prep_fused<<<8192, 256, 0, stream>>>(x, xb, w_qkv, wqkvT, w_proj, wpT);

  gemm_qkv<<<256, 512, 0, stream>>>(xb, wqkvT, qb, kb, vb);

  attn_kernel<<<512, 512, 0, stream>>>(qb, kb, vb, ctx);

  gemm_proj<<<512, 256, 0, stream>>>(ctx, wpT, out, b_proj);
}